// Round 1
// baseline (568.614 us; speedup 1.0000x reference)
//
#include <hip/hip_runtime.h>
#include <stdint.h>

typedef unsigned short u16;
typedef __bf16 bf16x8 __attribute__((ext_vector_type(8)));
typedef float f32x4 __attribute__((ext_vector_type(4)));
typedef unsigned short u16x8 __attribute__((ext_vector_type(8)));
typedef unsigned short u16x4 __attribute__((ext_vector_type(4)));

#define MFMA(a, b, c) __builtin_amdgcn_mfma_f32_16x16x32_bf16(a, b, c, 0, 0, 0)

static __device__ __forceinline__ u16 f2bf(float f) {
  union { float f; uint32_t u; } v; v.f = f;
  uint32_t r = 0x7FFFu + ((v.u >> 16) & 1u);
  return (u16)((v.u + r) >> 16);
}
static __device__ __forceinline__ float bf2f(u16 h) {
  union { uint32_t u; float f; } v; v.u = ((uint32_t)h) << 16;
  return v.f;
}

static __device__ __forceinline__ void gld_lds16(const u16* g, u16* l) {
  __builtin_amdgcn_global_load_lds(
      (const __attribute__((address_space(1))) void*)g,
      (__attribute__((address_space(3))) void*)l, 16, 0, 0);
}

// ---------------- elementwise cast x f32 -> bf16 ----------------
__global__ __launch_bounds__(256) void cast_f32_to_bf16(
    const float* __restrict__ in, u16* __restrict__ out, int n4) {
  int i = blockIdx.x * blockDim.x + threadIdx.x;
  if (i >= n4) return;
  const float4 v = ((const float4*)in)[i];
  u16x4 o;
  o[0] = f2bf(v.x); o[1] = f2bf(v.y); o[2] = f2bf(v.z); o[3] = f2bf(v.w);
  ((u16x4*)out)[i] = o;
}

// ---------------- transpose + cast: W [R][C] f32 -> Wt [C][R] bf16 ----------------
__global__ __launch_bounds__(256) void transpose_cast(
    const float* __restrict__ W, u16* __restrict__ Wt, int R, int C) {
  __shared__ float tile[32][33];
  const int bx = blockIdx.x * 32;  // C index
  const int by = blockIdx.y * 32;  // R index
  const int tx = threadIdx.x & 31, ty = threadIdx.x >> 5;
#pragma unroll
  for (int i = 0; i < 32; i += 8)
    tile[ty + i][tx] = W[(long)(by + ty + i) * C + bx + tx];
  __syncthreads();
#pragma unroll
  for (int i = 0; i < 32; i += 8)
    Wt[(long)(bx + ty + i) * R + by + tx] = f2bf(tile[tx][ty + i]);
}

// ---------------- RoPE in-place on q (with scale) and k ----------------
__global__ __launch_bounds__(256) void rope_kernel(
    u16* __restrict__ q, u16* __restrict__ k) {
  const int idx = blockIdx.x * blockDim.x + threadIdx.x;
  if (idx >= 4096 * 16 * 64) return;
  const int j = idx & 63;
  const int h = (idx >> 6) & 15;
  const int row = idx >> 10;       // b*2048 + n
  const int npos = row & 2047;
  // inv_freq = 10000^(-j/64) = 2^(-j*log2(10000)/64)
  const float inv_freq = exp2f(-0.20762051f * (float)j);
  const float pos = (float)npos * inv_freq;
  float s, c;
  sincosf(pos, &s, &c);
  const float scale = 0.08838834764831845f;  // 128^-0.5
  const long base = (long)row * 2048 + h * 128 + j;
  float q1 = bf2f(q[base]), q2 = bf2f(q[base + 64]);
  q[base]      = f2bf((q1 * c - q2 * s) * scale);
  q[base + 64] = f2bf((q2 * c + q1 * s) * scale);
  float k1 = bf2f(k[base]), k2 = bf2f(k[base + 64]);
  k[base]      = f2bf(k1 * c - k2 * s);
  k[base + 64] = f2bf(k2 * c + k1 * s);
}

// ---------------- m97-structure 128x128 GEMM, BK=32, 4 waves, 4x4 acc ----------------
// A: [M][K] bf16 row-major, Bt: [N][K] bf16 (weights pre-transposed), bias f32 [N]
template <int OUT_F32>
static __device__ __forceinline__ void gemm_tile(
    const u16* __restrict__ A, const u16* __restrict__ Bt,
    const float* __restrict__ bias, void* __restrict__ C,
    const int M, const int N, const int K,
    u16* As, u16* Bs, const int bx, const int by) {
  const int tid = threadIdx.x;
  const int wave = tid >> 6;
  const int lane = tid & 63;
  const int lr = lane & 15, hi = lane >> 4;
  const int row0 = by * 128, col0 = bx * 128;
  const int wr = (wave >> 1) * 64, wc = (wave & 1) * 64;

  // staging: elem e = (c*256 + tid)*8 -> row=(c*256+tid)>>2, col=(tid&3)*8
  const int srow = tid >> 2;
  const int scol = (tid & 3) * 8;
  const u16* gA0 = A + (long)(row0 + srow) * K + scol;
  const u16* gA1 = gA0 + (long)64 * K;
  const u16* gB0 = Bt + (long)(col0 + srow) * K + scol;
  const u16* gB1 = gB0 + (long)64 * K;
  u16* lA0 = As + wave * 512;          // wave-uniform LDS bases (+ lane*16B in HW)
  u16* lA1 = As + 2048 + wave * 512;
  u16* lB0 = Bs + wave * 512;
  u16* lB1 = Bs + 2048 + wave * 512;

  f32x4 acc[4][4] = {};

  for (int k0 = 0; k0 < K; k0 += 32) {
    __syncthreads();
    gld_lds16(gA0 + k0, lA0);
    gld_lds16(gA1 + k0, lA1);
    gld_lds16(gB0 + k0, lB0);
    gld_lds16(gB1 + k0, lB1);
    __syncthreads();
    bf16x8 af[4], bfr[4];
#pragma unroll
    for (int m = 0; m < 4; ++m)
      af[m] = *(const bf16x8*)&As[(wr + m * 16 + lr) * 32 + hi * 8];
#pragma unroll
    for (int n = 0; n < 4; ++n)
      bfr[n] = *(const bf16x8*)&Bs[(wc + n * 16 + lr) * 32 + hi * 8];
#pragma unroll
    for (int m = 0; m < 4; ++m)
#pragma unroll
      for (int n = 0; n < 4; ++n)
        acc[m][n] = MFMA(af[m], bfr[n], acc[m][n]);
  }

  // epilogue: D row = 4*hi + i, col = lr (within 16x16 tile)
#pragma unroll
  for (int n = 0; n < 4; ++n) {
    const int gcol = col0 + wc + n * 16 + lr;
    const float bb = bias[gcol];
#pragma unroll
    for (int m = 0; m < 4; ++m) {
      const int grow = row0 + wr + m * 16 + 4 * hi;
#pragma unroll
      for (int i = 0; i < 4; ++i) {
        const float v = acc[m][n][i] + bb;
        if (OUT_F32)
          ((float*)C)[(long)(grow + i) * N + gcol] = v;
        else
          ((u16*)C)[(long)(grow + i) * N + gcol] = f2bf(v);
      }
    }
  }
}

__global__ __launch_bounds__(256, 2) void gemm_qkv_kernel(
    const u16* __restrict__ xb,
    const u16* __restrict__ wtq, const u16* __restrict__ wtk, const u16* __restrict__ wtv,
    const float* __restrict__ bq, const float* __restrict__ bk, const float* __restrict__ bv,
    u16* __restrict__ qo, u16* __restrict__ ko, u16* __restrict__ vo) {
  __shared__ u16 As[4096], Bs[4096];
  const u16* Bt; const float* bias; u16* C;
  if (blockIdx.z == 0)      { Bt = wtq; bias = bq; C = qo; }
  else if (blockIdx.z == 1) { Bt = wtk; bias = bk; C = ko; }
  else                      { Bt = wtv; bias = bv; C = vo; }
  gemm_tile<0>(xb, Bt, bias, C, 4096, 2048, 2048, As, Bs, blockIdx.x, blockIdx.y);
}

__global__ __launch_bounds__(256, 2) void gemm_out_kernel(
    const u16* __restrict__ ao, const u16* __restrict__ wto,
    const float* __restrict__ bo, float* __restrict__ out) {
  __shared__ u16 As[4096], Bs[4096];
  gemm_tile<1>(ao, wto, bo, out, 4096, 2048, 2048, As, Bs, blockIdx.x, blockIdx.y);
}

// ---------------- causal flash attention ----------------
// Q/K/V/O layout: [b*2048][2048] bf16, head h at column h*128.
// Block: 4 waves x 16 q-rows (QBLK=64). KV tile = 32 rows.
__global__ __launch_bounds__(256, 2) void flash_attn_kernel(
    const u16* __restrict__ Q, const u16* __restrict__ K,
    const u16* __restrict__ V, u16* __restrict__ O) {
  __shared__ u16 Ks[32 * 128];     // [kv][d], XOR-swizzled rows
  __shared__ u16 Vt[128 * 64];     // [d][kv] transposed, 64-col padded, swizzled
  __shared__ u16 Ps[4][512];       // per-wave P [16][32], swizzled

  const int tid = threadIdx.x;
  const int w = tid >> 6;
  const int lane = tid & 63;
  const int lr = lane & 15, hi = lane >> 4;
  const int qt = gridDim.x - 1 - blockIdx.x;   // heavy (large-q0) blocks first
  const int q0 = qt * 64;
  const int bh = blockIdx.y;
  const long plane = (long)(bh >> 4) * 2048 * 2048 + (long)(bh & 15) * 128;
  const u16* Qb = Q + plane;
  const u16* Kb = K + plane;
  const u16* Vb = V + plane;

  // Q fragments in registers: qf[c] lane -> Q[q0+w*16+lr][c*32 + 8*hi + j]
  bf16x8 qf[4];
  {
    const long qrow = q0 + w * 16 + lr;
#pragma unroll
    for (int c = 0; c < 4; ++c)
      qf[c] = *(const bf16x8*)(Qb + qrow * 2048 + c * 32 + hi * 8);
  }

  f32x4 oacc[8] = {};
  float mrow[4] = {-3e38f, -3e38f, -3e38f, -3e38f};
  float lsum[4] = {0.f, 0.f, 0.f, 0.f};

  const int skv = tid >> 4;        // 0..15
  const int sd = (tid & 15) * 8;   // 0..120
  const int nkt = q0 / 32 + 2;

  char* KsB = (char*)Ks;
  char* VtB = (char*)Vt;
  char* PsB = (char*)(Ps[w]);

  for (int kt = 0; kt < nkt; ++kt) {
    __syncthreads();
    // ---- stage K (vector, swizzled) and V (transposed scatter, swizzled) ----
#pragma unroll
    for (int i = 0; i < 2; ++i) {
      const int kv = skv + 16 * i;
      const long grow = (long)(kt * 32 + kv) * 2048;
      const u16x8 kvec = *(const u16x8*)(Kb + grow + sd);
      const u16x8 vvec = *(const u16x8*)(Vb + grow + sd);
      *(u16x8*)(KsB + kv * 256 + ((sd * 2) ^ ((kv & 7) << 4))) = kvec;
#pragma unroll
      for (int j = 0; j < 8; ++j) {
        const int d = sd + j;
        const int swd = ((d ^ (d >> 3)) & 7) << 4;
        *(u16*)(VtB + d * 128 + ((kv * 2) ^ swd)) = vvec[j];
      }
    }
    __syncthreads();

    // ---- S = Q K^T : two 16-col blocks ----
    f32x4 s0 = {0.f, 0.f, 0.f, 0.f}, s1 = {0.f, 0.f, 0.f, 0.f};
#pragma unroll
    for (int c = 0; c < 4; ++c) {
      const int off = c * 64 + hi * 16;
      const bf16x8 kf0 = *(const bf16x8*)(KsB + lr * 256 + (off ^ ((lr & 7) << 4)));
      const bf16x8 kf1 = *(const bf16x8*)(KsB + (16 + lr) * 256 + (off ^ (((16 + lr) & 7) << 4)));
      s0 = MFMA(qf[c], kf0, s0);
      s1 = MFMA(qf[c], kf1, s1);
    }

    // ---- causal mask: row = q0+w*16+4*hi+i, col = kt*32 (+16) + lr ----
    const int qg = q0 + w * 16 + 4 * hi;
    const int kvb = kt * 32;
    if (kvb + 31 > q0 + w * 16) {
#pragma unroll
      for (int i = 0; i < 4; ++i) {
        if (kvb + lr > qg + i)      s0[i] = -1e30f;
        if (kvb + 16 + lr > qg + i) s1[i] = -1e30f;
      }
    }

    // ---- online softmax (per acc-reg row, 16-lane shuffle reduce) ----
#pragma unroll
    for (int i = 0; i < 4; ++i) {
      float mx = fmaxf(s0[i], s1[i]);
      mx = fmaxf(mx, __shfl_xor(mx, 1));
      mx = fmaxf(mx, __shfl_xor(mx, 2));
      mx = fmaxf(mx, __shfl_xor(mx, 4));
      mx = fmaxf(mx, __shfl_xor(mx, 8));
      const float mnew = fmaxf(mrow[i], mx);
      const float alpha = __expf(mrow[i] - mnew);
      mrow[i] = mnew;
      const float p0 = __expf(s0[i] - mnew);
      const float p1 = __expf(s1[i] - mnew);
      float ps = p0 + p1;
      ps += __shfl_xor(ps, 1);
      ps += __shfl_xor(ps, 2);
      ps += __shfl_xor(ps, 4);
      ps += __shfl_xor(ps, 8);
      lsum[i] = lsum[i] * alpha + ps;
#pragma unroll
      for (int n = 0; n < 8; ++n) oacc[n][i] *= alpha;
      // write P (bf16) to per-wave LDS, swizzled
      const int r = 4 * hi + i;
      const int sw = ((r ^ (r >> 2)) & 3) << 4;
      *(u16*)(PsB + r * 64 + ((lr * 2) ^ sw)) = f2bf(p0);
      *(u16*)(PsB + r * 64 + (((16 + lr) * 2) ^ sw)) = f2bf(p1);
    }
    asm volatile("s_waitcnt lgkmcnt(0)" ::: "memory");

    // ---- P fragment + PV ----
    const int psw = ((lr ^ (lr >> 2)) & 3) << 4;
    const bf16x8 pa = *(const bf16x8*)(PsB + lr * 64 + ((hi * 16) ^ psw));
#pragma unroll
    for (int n = 0; n < 8; ++n) {
      const int vr = n * 16 + lr;
      const int swv = ((vr ^ (vr >> 3)) & 7) << 4;
      const bf16x8 vf = *(const bf16x8*)(VtB + vr * 128 + ((hi * 16) ^ swv));
      oacc[n] = MFMA(pa, vf, oacc[n]);
    }
  }

  // ---- epilogue: normalize, write bf16 [b*2048+q][h*128+d] ----
  u16* Ob = (u16*)(O + plane);
#pragma unroll
  for (int i = 0; i < 4; ++i) {
    const float inv = 1.0f / lsum[i];
    const long orow = (long)(q0 + w * 16 + 4 * hi + i) * 2048;
#pragma unroll
    for (int n = 0; n < 8; ++n)
      Ob[orow + n * 16 + lr] = f2bf(oacc[n][i] * inv);
  }
}

// ---------------- launch ----------------
extern "C" void kernel_launch(void* const* d_in, const int* in_sizes, int n_in,
                              void* d_out, int out_size, void* d_ws, size_t ws_size,
                              hipStream_t stream) {
  const float* x  = (const float*)d_in[0];
  const float* Wq = (const float*)d_in[1];
  const float* bq = (const float*)d_in[2];
  const float* Wk = (const float*)d_in[3];
  const float* bk = (const float*)d_in[4];
  const float* Wv = (const float*)d_in[5];
  const float* bv = (const float*)d_in[6];
  const float* Wo = (const float*)d_in[7];
  const float* bo = (const float*)d_in[8];
  float* out = (float*)d_out;

  char* ws = (char*)d_ws;
  size_t off = 0;
  u16* xb   = (u16*)(ws + off); off += (size_t)4096 * 2048 * 2;
  u16* wtq  = (u16*)(ws + off); off += (size_t)2048 * 2048 * 2;
  u16* wtk  = (u16*)(ws + off); off += (size_t)2048 * 2048 * 2;
  u16* wtv  = (u16*)(ws + off); off += (size_t)2048 * 2048 * 2;
  u16* wto  = (u16*)(ws + off); off += (size_t)2048 * 2048 * 2;
  u16* qlin = (u16*)(ws + off); off += (size_t)4096 * 2048 * 2;
  u16* klin = (u16*)(ws + off); off += (size_t)4096 * 2048 * 2;
  u16* vlin = (u16*)(ws + off); off += (size_t)4096 * 2048 * 2;
  u16* aout = (u16*)(ws + off); off += (size_t)4096 * 2048 * 2;
  (void)ws_size; (void)in_sizes; (void)n_in; (void)out_size;

  cast_f32_to_bf16<<<dim3(8192), dim3(256), 0, stream>>>(x, xb, 4096 * 2048 / 4);
  dim3 tgrid(64, 64);
  transpose_cast<<<tgrid, dim3(256), 0, stream>>>(Wq, wtq, 2048, 2048);
  transpose_cast<<<tgrid, dim3(256), 0, stream>>>(Wk, wtk, 2048, 2048);
  transpose_cast<<<tgrid, dim3(256), 0, stream>>>(Wv, wtv, 2048, 2048);
  transpose_cast<<<tgrid, dim3(256), 0, stream>>>(Wo, wto, 2048, 2048);

  gemm_qkv_kernel<<<dim3(16, 32, 3), dim3(256), 0, stream>>>(
      xb, wtq, wtk, wtv, bq, bk, bv, qlin, klin, vlin);
  rope_kernel<<<dim3(16384), dim3(256), 0, stream>>>(qlin, klin);
  flash_attn_kernel<<<dim3(32, 32), dim3(256), 0, stream>>>(qlin, klin, vlin, aout);
  gemm_out_kernel<<<dim3(16, 32), dim3(256), 0, stream>>>(aout, wto, bo, out);
}

// Round 3
// 434.519 us; speedup vs baseline: 1.3086x; 1.3086x over previous
//
#include <hip/hip_runtime.h>
#include <stdint.h>

typedef unsigned short u16;
typedef __bf16 bf16x8 __attribute__((ext_vector_type(8)));
typedef float f32x4 __attribute__((ext_vector_type(4)));
typedef float f32x16 __attribute__((ext_vector_type(16)));
typedef unsigned short u16x8 __attribute__((ext_vector_type(8)));
typedef unsigned short u16x4 __attribute__((ext_vector_type(4)));

#define MFMA16(a, b, c) __builtin_amdgcn_mfma_f32_16x16x32_bf16(a, b, c, 0, 0, 0)
#define MFMA32(a, b, c) __builtin_amdgcn_mfma_f32_32x32x16_bf16(a, b, c, 0, 0, 0)

static __device__ __forceinline__ u16 f2bf(float f) {
  union { float f; uint32_t u; } v; v.f = f;
  uint32_t r = 0x7FFFu + ((v.u >> 16) & 1u);
  return (u16)((v.u + r) >> 16);
}
static __device__ __forceinline__ float bf2f(u16 h) {
  union { uint32_t u; float f; } v; v.u = ((uint32_t)h) << 16;
  return v.f;
}

static __device__ __forceinline__ void gld_lds16(const u16* g, u16* l) {
  __builtin_amdgcn_global_load_lds(
      (const __attribute__((address_space(1))) void*)g,
      (__attribute__((address_space(3))) void*)l, 16, 0, 0);
}

// ---------------- elementwise cast x f32 -> bf16 ----------------
__global__ __launch_bounds__(256) void cast_f32_to_bf16(
    const float* __restrict__ in, u16* __restrict__ out, int n4) {
  int i = blockIdx.x * blockDim.x + threadIdx.x;
  if (i >= n4) return;
  const float4 v = ((const float4*)in)[i];
  u16x4 o;
  o[0] = f2bf(v.x); o[1] = f2bf(v.y); o[2] = f2bf(v.z); o[3] = f2bf(v.w);
  ((u16x4*)out)[i] = o;
}

// ---------------- transpose + cast: W [R][C] f32 -> Wt [C][R] bf16 ----------------
__global__ __launch_bounds__(256) void transpose_cast(
    const float* __restrict__ W, u16* __restrict__ Wt, int R, int C) {
  __shared__ float tile[32][33];
  const int bx = blockIdx.x * 32;  // C index
  const int by = blockIdx.y * 32;  // R index
  const int tx = threadIdx.x & 31, ty = threadIdx.x >> 5;
#pragma unroll
  for (int i = 0; i < 32; i += 8)
    tile[ty + i][tx] = W[(long)(by + ty + i) * C + bx + tx];
  __syncthreads();
#pragma unroll
  for (int i = 0; i < 32; i += 8)
    Wt[(long)(bx + ty + i) * R + by + tx] = f2bf(tile[tx][ty + i]);
}

// ---------------- RoPE in-place on q (with scale) and k ----------------
__global__ __launch_bounds__(256) void rope_kernel(
    u16* __restrict__ q, u16* __restrict__ k) {
  const int idx = blockIdx.x * blockDim.x + threadIdx.x;
  if (idx >= 4096 * 16 * 64) return;
  const int j = idx & 63;
  const int h = (idx >> 6) & 15;
  const int row = idx >> 10;       // b*2048 + n
  const int npos = row & 2047;
  const float inv_freq = exp2f(-0.20762051f * (float)j);
  const float pos = (float)npos * inv_freq;
  float s, c;
  sincosf(pos, &s, &c);
  const float scale = 0.08838834764831845f;  // 128^-0.5
  const long base = (long)row * 2048 + h * 128 + j;
  float q1 = bf2f(q[base]), q2 = bf2f(q[base + 64]);
  q[base]      = f2bf((q1 * c - q2 * s) * scale);
  q[base + 64] = f2bf((q2 * c + q1 * s) * scale);
  float k1 = bf2f(k[base]), k2 = bf2f(k[base + 64]);
  k[base]      = f2bf(k1 * c - k2 * s);
  k[base + 64] = f2bf(k2 * c + k1 * s);
}

// ---------------- m97-structure 128x128 GEMM, BK=32, 4 waves, 4x4 acc ----------------
template <int OUT_F32>
static __device__ __forceinline__ void gemm_tile(
    const u16* __restrict__ A, const u16* __restrict__ Bt,
    const float* __restrict__ bias, void* __restrict__ C,
    const int M, const int N, const int K,
    u16* As, u16* Bs, const int bx, const int by) {
  const int tid = threadIdx.x;
  const int wave = tid >> 6;
  const int lane = tid & 63;
  const int lr = lane & 15, hi = lane >> 4;
  const int row0 = by * 128, col0 = bx * 128;
  const int wr = (wave >> 1) * 64, wc = (wave & 1) * 64;

  const int srow = tid >> 2;
  const int scol = (tid & 3) * 8;
  const u16* gA0 = A + (long)(row0 + srow) * K + scol;
  const u16* gA1 = gA0 + (long)64 * K;
  const u16* gB0 = Bt + (long)(col0 + srow) * K + scol;
  const u16* gB1 = gB0 + (long)64 * K;
  u16* lA0 = As + wave * 512;
  u16* lA1 = As + 2048 + wave * 512;
  u16* lB0 = Bs + wave * 512;
  u16* lB1 = Bs + 2048 + wave * 512;

  f32x4 acc[4][4] = {};

  for (int k0 = 0; k0 < K; k0 += 32) {
    __syncthreads();
    gld_lds16(gA0 + k0, lA0);
    gld_lds16(gA1 + k0, lA1);
    gld_lds16(gB0 + k0, lB0);
    gld_lds16(gB1 + k0, lB1);
    __syncthreads();
    bf16x8 af[4], bfr[4];
#pragma unroll
    for (int m = 0; m < 4; ++m)
      af[m] = *(const bf16x8*)&As[(wr + m * 16 + lr) * 32 + hi * 8];
#pragma unroll
    for (int n = 0; n < 4; ++n)
      bfr[n] = *(const bf16x8*)&Bs[(wc + n * 16 + lr) * 32 + hi * 8];
#pragma unroll
    for (int m = 0; m < 4; ++m)
#pragma unroll
      for (int n = 0; n < 4; ++n)
        acc[m][n] = MFMA16(af[m], bfr[n], acc[m][n]);
  }

#pragma unroll
  for (int n = 0; n < 4; ++n) {
    const int gcol = col0 + wc + n * 16 + lr;
    const float bb = bias[gcol];
#pragma unroll
    for (int m = 0; m < 4; ++m) {
      const int grow = row0 + wr + m * 16 + 4 * hi;
#pragma unroll
      for (int i = 0; i < 4; ++i) {
        const float v = acc[m][n][i] + bb;
        if (OUT_F32)
          ((float*)C)[(long)(grow + i) * N + gcol] = v;
        else
          ((u16*)C)[(long)(grow + i) * N + gcol] = f2bf(v);
      }
    }
  }
}

__global__ __launch_bounds__(256, 2) void gemm_qkv_kernel(
    const u16* __restrict__ xb,
    const u16* __restrict__ wtq, const u16* __restrict__ wtk, const u16* __restrict__ wtv,
    const float* __restrict__ bq, const float* __restrict__ bk, const float* __restrict__ bv,
    u16* __restrict__ qo, u16* __restrict__ ko, u16* __restrict__ vo) {
  __shared__ u16 As[4096], Bs[4096];
  const u16* Bt; const float* bias; u16* C;
  if (blockIdx.z == 0)      { Bt = wtq; bias = bq; C = qo; }
  else if (blockIdx.z == 1) { Bt = wtk; bias = bk; C = ko; }
  else                      { Bt = wtv; bias = bv; C = vo; }
  gemm_tile<0>(xb, Bt, bias, C, 4096, 2048, 2048, As, Bs, blockIdx.x, blockIdx.y);
}

__global__ __launch_bounds__(256, 2) void gemm_out_kernel(
    const u16* __restrict__ ao, const u16* __restrict__ wto,
    const float* __restrict__ bo, float* __restrict__ out) {
  __shared__ u16 As[4096], Bs[4096];
  gemm_tile<1>(ao, wto, bo, out, 4096, 2048, 2048, As, Bs, blockIdx.x, blockIdx.y);
}

// ---------------- causal flash attention, swapped-QK^T 32x32 structure ----------------
// Q/K/V/O layout: [b*2048][2048] bf16, head h at columns h*128..+127.
// Block: 4 waves x 32 q-rows (QBLK=128), KVBLK=64, double-buffered K/V LDS.
// K LDS: [64][128] bf16, byte-col XOR-swizzled by (row&15)<<4, staged linearly via
//   global_load_lds with pre-swizzled per-lane SOURCE addresses (G21).
// V LDS: 8 d-blocks of [64 kv][16 d] row-major, block stride 2080B, consumed by
//   ds_read_b64_tr_b16: each 16-lane group supplies tile_base + (lane&15)*8 so the
//   group gathers a 4(kv)x16(d) tile and lane receives d-column (lane&15).
__global__ __launch_bounds__(256, 2) void flash_attn_kernel(
    const u16* __restrict__ Q, const u16* __restrict__ K,
    const u16* __restrict__ V, u16* __restrict__ O) {
  __shared__ u16 Ks[2][8192];
  __shared__ char Vs[2][16640];

  const int tid = threadIdx.x;
  const int w = tid >> 6;
  const int lane = tid & 63;
  const int l31 = lane & 31, hi5 = lane >> 5, l15 = lane & 15, bit4 = (lane >> 4) & 1;
  const int qt = 15 - blockIdx.x;            // heavy blocks first
  const int q0 = qt * 128;
  const int bh = blockIdx.y;
  const long plane = (long)(bh >> 4) * 2048 * 2048 + (long)(bh & 15) * 128;
  const u16* Qb = Q + plane;
  const u16* Kb = K + plane;
  const u16* Vb = V + plane;
  const int qrow = q0 + w * 32 + l31;

  // Q B-frags in registers: qf[c] = Q[qrow][c*16 + hi5*8 .. +8]
  bf16x8 qf[8];
#pragma unroll
  for (int c = 0; c < 8; ++c)
    qf[c] = *(const bf16x8*)(Qb + (long)qrow * 2048 + c * 16 + hi5 * 8);

  // staging source offsets (elements within the kv-tile)
  int srcKoff[4], srcVoff[4];
#pragma unroll
  for (int cc = 0; cc < 4; ++cc) {
    const int ci = cc * 256 + tid;
    const int krow = ci >> 4;                 // 16 chunks per 256B row
    const int cL = (ci & 15) * 16;            // linear LDS byte col
    srcKoff[cc] = krow * 2048 + ((cL ^ ((krow & 15) << 4)) >> 1);
    const int dg16 = ci >> 7;                 // V: 128 chunks per d-block
    const int w2 = ci & 127;
    srcVoff[cc] = (w2 >> 1) * 2048 + dg16 * 16 + (w2 & 1) * 8;
  }

  f32x16 ot[4] = {};
  float m = -3e38f, lp = 0.f;
  const int nkt = 2 * qt + 2;
  const int swzk = l15 << 4;
  const int vbase = bit4 * 2080 + hi5 * 256 + l15 * 8;   // FIXED: 8B/lane chunk stride

  auto STAGE = [&](int buf, int kt1) {
    const long koff = (long)kt1 * 131072;     // 64 rows * 2048 elems
#pragma unroll
    for (int cc = 0; cc < 4; ++cc) {
      gld_lds16(Kb + koff + srcKoff[cc], &Ks[buf][cc * 2048 + w * 512]);
      const int ci0 = cc * 256 + w * 64;
      gld_lds16(Vb + koff + srcVoff[cc],
                (u16*)&Vs[buf][(ci0 >> 7) * 2080 + (ci0 & 127) * 16]);
    }
  };

  STAGE(0, 0);
  for (int kt = 0; kt < nkt; ++kt) {
    __syncthreads();                          // drains prev STAGE (vmcnt0) + sync
    if (kt + 1 < nkt) STAGE((kt + 1) & 1, kt + 1);
    const int kv0 = kt * 64;
    if (kv0 > q0 + w * 32 + 31) continue;     // wave fully masked: skip compute

    const char* KT = (const char*)Ks[kt & 1];
    const char* VT = Vs[kt & 1];

    // ---- S^T = K Q^T (two 32-kv groups) ----
    f32x16 sa[2] = {};
#pragma unroll
    for (int g = 0; g < 2; ++g) {
      const int rowb = (g * 32 + l31) * 256;
#pragma unroll
      for (int c = 0; c < 8; ++c) {
        const int ab = rowb + ((c * 32 + hi5 * 16) ^ swzk);
        const bf16x8 kf = *(const bf16x8*)(KT + ab);
        sa[g] = MFMA32(kf, qf[c], sa[g]);
      }
    }

    // ---- causal mask (S^T: row kv = (r&3)+8*(r>>2)+4*hi5, col q = l31) ----
    if (kv0 + 63 > q0 + w * 32) {
#pragma unroll
      for (int g = 0; g < 2; ++g)
#pragma unroll
        for (int r = 0; r < 16; ++r) {
          const int kv = kv0 + g * 32 + (r & 3) + 8 * (r >> 2) + 4 * hi5;
          if (kv > qrow) sa[g][r] = -1e30f;
        }
    }

    // ---- online softmax, fully in-register (lane pair l <-> l^32 shares q) ----
    float pm = -3e38f;
#pragma unroll
    for (int g = 0; g < 2; ++g)
#pragma unroll
      for (int r = 0; r < 16; ++r) pm = fmaxf(pm, sa[g][r]);
    pm = fmaxf(pm, __shfl_xor(pm, 32));
    const float mnew = fmaxf(m, pm);
    const float alpha = __expf(m - mnew);
    float psum = 0.f;
#pragma unroll
    for (int g = 0; g < 2; ++g)
#pragma unroll
      for (int r = 0; r < 16; ++r) {
        const float pv = __expf(sa[g][r] - mnew);
        sa[g][r] = pv;
        psum += pv;
      }
    lp = lp * alpha + psum;
    m = mnew;
#pragma unroll
    for (int dg = 0; dg < 4; ++dg) ot[dg] *= alpha;

    // ---- P^T B-frags: cvt_pk pairs + cross-half exchange ----
    uint32_t pk[2][8];
#pragma unroll
    for (int g = 0; g < 2; ++g)
#pragma unroll
      for (int k2 = 0; k2 < 8; ++k2)
        asm("v_cvt_pk_bf16_f32 %0, %1, %2"
            : "=v"(pk[g][k2]) : "v"(sa[g][2 * k2]), "v"(sa[g][2 * k2 + 1]));

    bf16x8 pfrag[4];
#pragma unroll
    for (int kc = 0; kc < 4; ++kc) {
      const int g = kc >> 1, b = 4 * (kc & 1);
      const uint32_t lo0 = pk[g][b],     lo1 = pk[g][b + 1];
      const uint32_t hh0 = pk[g][b + 2], hh1 = pk[g][b + 3];
      const uint32_t s0v = hi5 ? lo0 : hh0;   // send opposite-half block to pair
      const uint32_t s1v = hi5 ? lo1 : hh1;
      const uint32_t r0 = (uint32_t)__shfl_xor((int)s0v, 32);
      const uint32_t r1 = (uint32_t)__shfl_xor((int)s1v, 32);
      union { uint32_t u[4]; bf16x8 v; } fu;
      fu.u[0] = hi5 ? r0 : lo0;
      fu.u[1] = hi5 ? r1 : lo1;
      fu.u[2] = hi5 ? hh0 : r0;
      fu.u[3] = hi5 ? hh1 : r1;
      pfrag[kc] = fu.v;
    }

    // ---- O^T += V^T P^T  (V^T A-frags via hw transpose read) ----
#pragma unroll
    for (int dg = 0; dg < 4; ++dg) {
      unsigned long long t[8];
#pragma unroll
      for (int kc = 0; kc < 4; ++kc)
#pragma unroll
        for (int r = 0; r < 2; ++r) {
          const uint32_t a = (uint32_t)(size_t)VT + (uint32_t)(vbase + dg * 4160 + kc * 512 + r * 128);
          asm volatile("ds_read_b64_tr_b16 %0, %1" : "=v"(t[kc * 2 + r]) : "v"(a));
        }
      asm volatile("s_waitcnt lgkmcnt(0)" ::: "memory");
      __builtin_amdgcn_sched_barrier(0);
#pragma unroll
      for (int kc = 0; kc < 4; ++kc) {
        union { unsigned long long q[2]; bf16x8 v; } vu;
        vu.q[0] = t[kc * 2]; vu.q[1] = t[kc * 2 + 1];
        ot[dg] = MFMA32(vu.v, pfrag[kc], ot[dg]);
      }
    }
  }

  // ---- epilogue: normalize, write O^T -> O[q][d] (8B packs) ----
  const float lt = lp + __shfl_xor(lp, 32);
  const float inv = 1.0f / lt;
  u16* Ob = (u16*)O + plane;
#pragma unroll
  for (int dg = 0; dg < 4; ++dg)
#pragma unroll
    for (int rq = 0; rq < 4; ++rq) {
      u16x4 pk4;
#pragma unroll
      for (int j = 0; j < 4; ++j) pk4[j] = f2bf(ot[dg][rq * 4 + j] * inv);
      *(u16x4*)(Ob + (long)qrow * 2048 + dg * 32 + 8 * rq + 4 * hi5) = pk4;
    }
}

// ---------------- launch ----------------
extern "C" void kernel_launch(void* const* d_in, const int* in_sizes, int n_in,
                              void* d_out, int out_size, void* d_ws, size_t ws_size,
                              hipStream_t stream) {
  const float* x  = (const float*)d_in[0];
  const float* Wq = (const float*)d_in[1];
  const float* bq = (const float*)d_in[2];
  const float* Wk = (const float*)d_in[3];
  const float* bk = (const float*)d_in[4];
  const float* Wv = (const float*)d_in[5];
  const float* bv = (const float*)d_in[6];
  const float* Wo = (const float*)d_in[7];
  const float* bo = (const float*)d_in[8];
  float* out = (float*)d_out;

  char* ws = (char*)d_ws;
  size_t off = 0;
  u16* xb   = (u16*)(ws + off); off += (size_t)4096 * 2048 * 2;
  u16* wtq  = (u16*)(ws + off); off += (size_t)2048 * 2048 * 2;
  u16* wtk  = (u16*)(ws + off); off += (size_t)2048 * 2048 * 2;
  u16* wtv  = (u16*)(ws + off); off += (size_t)2048 * 2048 * 2;
  u16* wto  = (u16*)(ws + off); off += (size_t)2048 * 2048 * 2;
  u16* qlin = (u16*)(ws + off); off += (size_t)4096 * 2048 * 2;
  u16* klin = (u16*)(ws + off); off += (size_t)4096 * 2048 * 2;
  u16* vlin = (u16*)(ws + off); off += (size_t)4096 * 2048 * 2;
  u16* aout = (u16*)(ws + off); off += (size_t)4096 * 2048 * 2;
  (void)ws_size; (void)in_sizes; (void)n_in; (void)out_size;

  cast_f32_to_bf16<<<dim3(8192), dim3(256), 0, stream>>>(x, xb, 4096 * 2048 / 4);
  dim3 tgrid(64, 64);
  transpose_cast<<<tgrid, dim3(256), 0, stream>>>(Wq, wtq, 2048, 2048);
  transpose_cast<<<tgrid, dim3(256), 0, stream>>>(Wk, wtk, 2048, 2048);
  transpose_cast<<<tgrid, dim3(256), 0, stream>>>(Wv, wtv, 2048, 2048);
  transpose_cast<<<tgrid, dim3(256), 0, stream>>>(Wo, wto, 2048, 2048);

  gemm_qkv_kernel<<<dim3(16, 32, 3), dim3(256), 0, stream>>>(
      xb, wtq, wtk, wtv, bq, bk, bv, qlin, klin, vlin);
  rope_kernel<<<dim3(16384), dim3(256), 0, stream>>>(qlin, klin);
  flash_attn_kernel<<<dim3(16, 32), dim3(256), 0, stream>>>(qlin, klin, vlin, aout);
  gemm_out_kernel<<<dim3(16, 32), dim3(256), 0, stream>>>(aout, wto, bo, out);
}